// Round 1
// baseline (236.970 us; speedup 1.0000x reference)
//
#include <hip/hip_runtime.h>
#include <math.h>

// LayerSumSimple: K-level chained cummax-of-sums == max-plus affine scan with
// 8-element state. 3-pass chunk-parallel scan:
//   pass1: per-chunk max-plus affine summary (28 lower-tri A entries + 8 c)
//   pass2: sequential compose across chunks -> inflow state per chunk
//   pass3: re-scan each chunk from true inflow, emit outputs
namespace {
constexpr int BB   = 8;
constexpr int TT   = 8192;
constexpr int DD   = 256;
constexpr int KK   = 8;
constexpr int TOUT = TT - KK + 1;       // 8185
constexpr int NSUM = 44;                // 8 c-vector + 28 strict-lower A

__host__ __device__ __forceinline__ constexpr int tri(int k, int j) {
    return 8 + k * (k - 1) / 2 + j;     // k in [1,8), j < k
}

// ---- pass 1: one block per (b, chunk); thread d = channel d ----
__global__ __launch_bounds__(256) void pass1_summaries(
    const float* __restrict__ X, const float* __restrict__ W,
    const float* __restrict__ Bv, float* __restrict__ sum, int C, int L)
{
    const int b = blockIdx.x / C;
    const int c = blockIdx.x % C;
    const int d = threadIdx.x;

    float wk[KK], bk[KK];
    #pragma unroll
    for (int k = 0; k < KK; ++k) { wk[k] = W[k * DD + d]; bk[k] = Bv[k * DD + d]; }

    // A = identity (diag 0 implicit, strict-lower tracked), c = -inf
    float cv[KK];
    float A[KK][KK];
    #pragma unroll
    for (int k = 0; k < KK; ++k) {
        cv[k] = -INFINITY;
        #pragma unroll
        for (int j = 0; j < KK; ++j) A[k][j] = -INFINITY;
    }

    const float* xp = X + ((long)b * TT + (long)c * L) * DD + d;
    #pragma unroll 2
    for (int i = 0; i < L; ++i) {
        const float x = xp[(long)i * DD];
        float g[KK];
        #pragma unroll
        for (int k = 0; k < KK; ++k) g[k] = fmaf(x, wk[k], bk[k]);
        // A <- M_t (x) A ; c <- M_t (x) c (+) v_t  — descending k uses OLD row k-1
        #pragma unroll
        for (int k = KK - 1; k >= 1; --k) {
            #pragma unroll
            for (int j = 0; j < k - 1; ++j)
                A[k][j] = fmaxf(A[k][j], g[k] + A[k - 1][j]);
            A[k][k - 1] = fmaxf(A[k][k - 1], g[k]);  // A[k-1][k-1] == 0 (diag)
            cv[k] = fmaxf(cv[k], g[k] + cv[k - 1]);
        }
        cv[0] = fmaxf(cv[0], g[0]);
    }

    float* sp = sum + (((long)b * C + c) * NSUM) * DD + d;
    #pragma unroll
    for (int k = 0; k < KK; ++k) sp[k * DD] = cv[k];
    #pragma unroll
    for (int k = 1; k < KK; ++k) {
        #pragma unroll
        for (int j = 0; j < k; ++j) sp[tri(k, j) * DD] = A[k][j];
    }
}

// ---- pass 2: one thread per (b, d); sequentially compose chunk maps ----
__global__ __launch_bounds__(256) void pass2_combine(
    const float* __restrict__ sum, float* __restrict__ infl, int C)
{
    const int b = blockIdx.x;
    const int d = threadIdx.x;
    float s[KK];
    #pragma unroll
    for (int k = 0; k < KK; ++k) s[k] = -INFINITY;

    for (int c = 0; c < C; ++c) {
        float* ip = infl + (((long)b * C + c) * KK) * DD + d;
        #pragma unroll
        for (int k = 0; k < KK; ++k) ip[k * DD] = s[k];   // inflow BEFORE chunk c

        const float* sp = sum + (((long)b * C + c) * NSUM) * DD + d;
        float ns[KK];
        #pragma unroll
        for (int k = 0; k < KK; ++k) ns[k] = fmaxf(sp[k * DD], s[k]); // c[k], diag
        #pragma unroll
        for (int k = 1; k < KK; ++k) {
            #pragma unroll
            for (int j = 0; j < k; ++j)
                ns[k] = fmaxf(ns[k], sp[tri(k, j) * DD] + s[j]);
        }
        #pragma unroll
        for (int k = 0; k < KK; ++k) s[k] = ns[k];
    }
}

// ---- pass 3: one block per (b, chunk); plain 8-state scan, emit outputs ----
__global__ __launch_bounds__(256) void pass3_scan(
    const float* __restrict__ X, const float* __restrict__ W,
    const float* __restrict__ Bv, const float* __restrict__ infl,
    float* __restrict__ out, int C, int L)
{
    const int b = blockIdx.x / C;
    const int c = blockIdx.x % C;
    const int d = threadIdx.x;

    float wk[KK], bk[KK];
    #pragma unroll
    for (int k = 0; k < KK; ++k) { wk[k] = W[k * DD + d]; bk[k] = Bv[k * DD + d]; }

    float s[KK];
    const float* ip = infl + (((long)b * C + c) * KK) * DD + d;
    #pragma unroll
    for (int k = 0; k < KK; ++k) s[k] = ip[k * DD];

    const int t0 = c * L;
    const float* xp = X + ((long)b * TT + t0) * DD + d;
    float* op = out + (long)b * TOUT * DD + d;

    #pragma unroll 4
    for (int i = 0; i < L; ++i) {
        const float x = xp[(long)i * DD];
        float g[KK];
        #pragma unroll
        for (int k = 0; k < KK; ++k) g[k] = fmaf(x, wk[k], bk[k]);
        #pragma unroll
        for (int k = KK - 1; k >= 1; --k) s[k] = fmaxf(s[k], s[k - 1] + g[k]);
        s[0] = fmaxf(s[0], g[0]);
        const int t = t0 + i;
        if (t >= KK - 1) op[(long)(t - (KK - 1)) * DD] = s[KK - 1];
    }
}
} // namespace

extern "C" void kernel_launch(void* const* d_in, const int* in_sizes, int n_in,
                              void* d_out, int out_size, void* d_ws, size_t ws_size,
                              hipStream_t stream)
{
    const float* X  = (const float*)d_in[0];
    const float* W  = (const float*)d_in[1];
    const float* Bv = (const float*)d_in[2];
    float* out = (float*)d_out;

    // Largest chunk count whose summaries+inflows fit the workspace.
    int C = 64;
    while (C > 1 && (size_t)BB * C * (NSUM + KK) * DD * sizeof(float) > ws_size)
        C >>= 1;
    const int L = TT / C;

    float* sum  = (float*)d_ws;
    float* infl = sum + (size_t)BB * C * NSUM * DD;

    pass1_summaries<<<BB * C, 256, 0, stream>>>(X, W, Bv, sum, C, L);
    pass2_combine<<<BB, 256, 0, stream>>>(sum, infl, C);
    pass3_scan<<<BB * C, 256, 0, stream>>>(X, W, Bv, infl, out, C, L);
}

// Round 2
// 196.579 us; speedup vs baseline: 1.2055x; 1.2055x over previous
//
#include <hip/hip_runtime.h>
#include <math.h>

// LayerSumSimple: K-level chained cummax-of-sums == max-plus affine scan with
// 8-element state s:  s[k] <- max(s[k], s[k-1] + g_k(t)),  g_k = x*w[k]+b[k].
// Chunk-parallel scan:
//   pass1 : per-chunk max-plus affine summary (28 strict-lower A + 8 c)
//   pass2a: compose 16-chunk groups into group maps (parallel over groups)
//   pass2b: serial scan over NG group maps -> group inflow states
//   pass2c: replay chunk maps within each group -> per-chunk inflow states
//   pass3 : re-scan each chunk from true inflow, emit outputs
namespace {
constexpr int BB   = 8;
constexpr int TT   = 8192;
constexpr int DD   = 256;
constexpr int KK   = 8;
constexpr int TOUT = TT - KK + 1;       // 8185
constexpr int NSUM = 44;                // 8 c-vector + 28 strict-lower A

__host__ __device__ __forceinline__ constexpr int tri(int k, int j) {
    return 8 + k * (k - 1) / 2 + j;     // k in [1,8), j < k
}

// ---- pass 1: one block per (b, chunk); thread d = channel ----
__global__ __launch_bounds__(256, 4) void pass1_summaries(
    const float* __restrict__ X, const float* __restrict__ W,
    const float* __restrict__ Bv, float* __restrict__ sum, int C, int L)
{
    const int b = blockIdx.x / C;
    const int c = blockIdx.x % C;
    const int d = threadIdx.x;

    float wk[KK], bk[KK];
    #pragma unroll
    for (int k = 0; k < KK; ++k) { wk[k] = W[k * DD + d]; bk[k] = Bv[k * DD + d]; }

    float cv[KK];
    float A[KK][KK];
    #pragma unroll
    for (int k = 0; k < KK; ++k) {
        cv[k] = -INFINITY;
        #pragma unroll
        for (int j = 0; j < KK; ++j) A[k][j] = -INFINITY;
    }

    const float* xp = X + ((long)b * TT + (long)c * L) * DD + d;
    #pragma unroll 2
    for (int i = 0; i < L; ++i) {
        const float x = xp[(long)i * DD];
        float g[KK];
        #pragma unroll
        for (int k = 0; k < KK; ++k) g[k] = fmaf(x, wk[k], bk[k]);
        #pragma unroll
        for (int k = KK - 1; k >= 1; --k) {
            #pragma unroll
            for (int j = 0; j < k - 1; ++j)
                A[k][j] = fmaxf(A[k][j], g[k] + A[k - 1][j]);
            A[k][k - 1] = fmaxf(A[k][k - 1], g[k]);  // A[k-1][k-1] == 0 (diag)
            cv[k] = fmaxf(cv[k], g[k] + cv[k - 1]);
        }
        cv[0] = fmaxf(cv[0], g[0]);
    }

    float* sp = sum + (((long)b * C + c) * NSUM) * DD + d;
    #pragma unroll
    for (int k = 0; k < KK; ++k) sp[k * DD] = cv[k];
    #pragma unroll
    for (int k = 1; k < KK; ++k) {
        #pragma unroll
        for (int j = 0; j < k; ++j) sp[tri(k, j) * DD] = A[k][j];
    }
}

// ---- pass 2a: one block per (b, group); compose G chunk maps into one ----
__global__ __launch_bounds__(256) void pass2a_groups(
    const float* __restrict__ sum, float* __restrict__ gsum, int C, int G)
{
    const int NG = C / G;
    const int b = blockIdx.x / NG;
    const int g = blockIdx.x % NG;
    const int d = threadIdx.x;

    float R[KK][KK], cv[KK];       // accumulated map (strict-lower R, c-vec)
    #pragma unroll
    for (int i = 0; i < KK; ++i) {
        cv[i] = -INFINITY;
        #pragma unroll
        for (int j = 0; j < KK; ++j) R[i][j] = -INFINITY;
    }

    for (int c = g * G; c < (g + 1) * G; ++c) {
        const float* sp = sum + (((long)b * C + c) * NSUM) * DD + d;
        float a2[KK][KK], c2[KK];
        #pragma unroll
        for (int i = 0; i < KK; ++i) c2[i] = sp[i * DD];
        #pragma unroll
        for (int i = 1; i < KK; ++i) {
            #pragma unroll
            for (int j = 0; j < i; ++j) a2[i][j] = sp[tri(i, j) * DD];
        }
        // nc[i] = max(c2[i], cv[i], max_{j<i} a2[i][j]+cv[j])
        float nc[KK];
        #pragma unroll
        for (int i = 0; i < KK; ++i) {
            float v = fmaxf(c2[i], cv[i]);
            #pragma unroll
            for (int j = 0; j < i; ++j) v = fmaxf(v, a2[i][j] + cv[j]);
            nc[i] = v;
        }
        // nR[i][j] = max(R[i][j], a2[i][j], max_{j<m<i} a2[i][m]+R[m][j])
        float nR[KK][KK];
        #pragma unroll
        for (int i = 1; i < KK; ++i) {
            #pragma unroll
            for (int j = 0; j < i; ++j) {
                float v = fmaxf(R[i][j], a2[i][j]);
                #pragma unroll
                for (int m = j + 1; m < i; ++m) v = fmaxf(v, a2[i][m] + R[m][j]);
                nR[i][j] = v;
            }
        }
        #pragma unroll
        for (int i = 0; i < KK; ++i) {
            cv[i] = nc[i];
            #pragma unroll
            for (int j = 0; j < i; ++j) R[i][j] = nR[i][j];
        }
    }

    float* gp = gsum + (((long)b * NG + g) * NSUM) * DD + d;
    #pragma unroll
    for (int i = 0; i < KK; ++i) gp[i * DD] = cv[i];
    #pragma unroll
    for (int i = 1; i < KK; ++i) {
        #pragma unroll
        for (int j = 0; j < i; ++j) gp[tri(i, j) * DD] = R[i][j];
    }
}

// ---- pass 2b: one block per b; serial scan over NG group maps ----
__global__ __launch_bounds__(256) void pass2b_scan_groups(
    const float* __restrict__ gsum, float* __restrict__ ginfl, int NG)
{
    const int b = blockIdx.x;
    const int d = threadIdx.x;
    float s[KK];
    #pragma unroll
    for (int k = 0; k < KK; ++k) s[k] = -INFINITY;

    for (int g = 0; g < NG; ++g) {
        float* ip = ginfl + (((long)b * NG + g) * KK) * DD + d;
        #pragma unroll
        for (int k = 0; k < KK; ++k) ip[k * DD] = s[k];   // inflow BEFORE group g

        const float* gp = gsum + (((long)b * NG + g) * NSUM) * DD + d;
        float ns[KK];
        #pragma unroll
        for (int k = 0; k < KK; ++k) ns[k] = fmaxf(gp[k * DD], s[k]);
        #pragma unroll
        for (int k = 1; k < KK; ++k) {
            #pragma unroll
            for (int j = 0; j < k; ++j)
                ns[k] = fmaxf(ns[k], gp[tri(k, j) * DD] + s[j]);
        }
        #pragma unroll
        for (int k = 0; k < KK; ++k) s[k] = ns[k];
    }
}

// ---- pass 2c: one block per (b, group); replay chunk maps -> chunk inflows ----
__global__ __launch_bounds__(256) void pass2c_chunk_inflows(
    const float* __restrict__ sum, const float* __restrict__ ginfl,
    float* __restrict__ infl, int C, int G)
{
    const int NG = C / G;
    const int b = blockIdx.x / NG;
    const int g = blockIdx.x % NG;
    const int d = threadIdx.x;

    float s[KK];
    const float* gp = ginfl + (((long)b * NG + g) * KK) * DD + d;
    #pragma unroll
    for (int k = 0; k < KK; ++k) s[k] = gp[k * DD];

    for (int c = g * G; c < (g + 1) * G; ++c) {
        float* ip = infl + (((long)b * C + c) * KK) * DD + d;
        #pragma unroll
        for (int k = 0; k < KK; ++k) ip[k * DD] = s[k];   // inflow BEFORE chunk c

        const float* sp = sum + (((long)b * C + c) * NSUM) * DD + d;
        float ns[KK];
        #pragma unroll
        for (int k = 0; k < KK; ++k) ns[k] = fmaxf(sp[k * DD], s[k]);
        #pragma unroll
        for (int k = 1; k < KK; ++k) {
            #pragma unroll
            for (int j = 0; j < k; ++j)
                ns[k] = fmaxf(ns[k], sp[tri(k, j) * DD] + s[j]);
        }
        #pragma unroll
        for (int k = 0; k < KK; ++k) s[k] = ns[k];
    }
}

// ---- pass 3: one block per (b, chunk); plain 8-state scan, emit outputs ----
__global__ __launch_bounds__(256, 4) void pass3_scan(
    const float* __restrict__ X, const float* __restrict__ W,
    const float* __restrict__ Bv, const float* __restrict__ infl,
    float* __restrict__ out, int C, int L)
{
    const int b = blockIdx.x / C;
    const int c = blockIdx.x % C;
    const int d = threadIdx.x;

    float wk[KK], bk[KK];
    #pragma unroll
    for (int k = 0; k < KK; ++k) { wk[k] = W[k * DD + d]; bk[k] = Bv[k * DD + d]; }

    float s[KK];
    const float* ip = infl + (((long)b * C + c) * KK) * DD + d;
    #pragma unroll
    for (int k = 0; k < KK; ++k) s[k] = ip[k * DD];

    const int t0 = c * L;
    const float* xp = X + ((long)b * TT + t0) * DD + d;
    float* op = out + (long)b * TOUT * DD + d;

    #pragma unroll 4
    for (int i = 0; i < L; ++i) {
        const float x = xp[(long)i * DD];
        float g[KK];
        #pragma unroll
        for (int k = 0; k < KK; ++k) g[k] = fmaf(x, wk[k], bk[k]);
        #pragma unroll
        for (int k = KK - 1; k >= 1; --k) s[k] = fmaxf(s[k], s[k - 1] + g[k]);
        s[0] = fmaxf(s[0], g[0]);
        const int t = t0 + i;
        if (t >= KK - 1) op[(long)(t - (KK - 1)) * DD] = s[KK - 1];
    }
}
} // namespace

extern "C" void kernel_launch(void* const* d_in, const int* in_sizes, int n_in,
                              void* d_out, int out_size, void* d_ws, size_t ws_size,
                              hipStream_t stream)
{
    const float* X  = (const float*)d_in[0];
    const float* W  = (const float*)d_in[1];
    const float* Bv = (const float*)d_in[2];
    float* out = (float*)d_out;

    // Largest chunk count (<=128) whose summaries+inflows+group arrays fit ws.
    int C = 128;
    int G, NG;
    for (;;) {
        G  = (C >= 16) ? 16 : C;
        NG = C / G;
        size_t need = ((size_t)BB * C * (NSUM + KK) +
                       (size_t)BB * NG * (NSUM + KK)) * DD * sizeof(float);
        if (need <= ws_size || C <= 2) break;
        C >>= 1;
    }
    const int L = TT / C;

    float* sum   = (float*)d_ws;
    float* infl  = sum   + (size_t)BB * C  * NSUM * DD;
    float* gsum  = infl  + (size_t)BB * C  * KK   * DD;
    float* ginfl = gsum  + (size_t)BB * NG * NSUM * DD;

    pass1_summaries<<<BB * C, 256, 0, stream>>>(X, W, Bv, sum, C, L);
    pass2a_groups<<<BB * NG, 256, 0, stream>>>(sum, gsum, C, G);
    pass2b_scan_groups<<<BB, 256, 0, stream>>>(gsum, ginfl, NG);
    pass2c_chunk_inflows<<<BB * NG, 256, 0, stream>>>(sum, ginfl, infl, C, G);
    pass3_scan<<<BB * C, 256, 0, stream>>>(X, W, Bv, infl, out, C, L);
}

// Round 3
// 190.349 us; speedup vs baseline: 1.2449x; 1.0327x over previous
//
#include <hip/hip_runtime.h>
#include <math.h>

// LayerSumSimple: K-level chained cummax-of-sums == max-plus affine scan with
// 8-element state s:  s[k] <- max(s[k], s[k-1] + g_k(t)),  g_k = x*w[k]+b[k].
// Chunk-parallel scan:
//   pass1 : per-chunk max-plus affine summary (28 strict-lower A + 8 c)
//   pass2a: compose G-chunk groups into group maps (parallel over groups)
//   pass2b: serial scan over NG group maps -> group inflow states (apply-only)
//   pass2c: replay chunk maps within each group -> chunk inflows (apply-only)
//   pass3 : re-scan each chunk from true inflow (float2/thread), emit outputs
namespace {
constexpr int BB   = 8;
constexpr int TT   = 8192;
constexpr int DD   = 256;
constexpr int KK   = 8;
constexpr int TOUT = TT - KK + 1;       // 8185
constexpr int NSUM = 36;                // 8 c-vector + 28 strict-lower A

__host__ __device__ __forceinline__ constexpr int tri(int k, int j) {
    return 8 + k * (k - 1) / 2 + j;     // k in [1,8), j < k  (max = 35)
}

// one time-step of the summary recurrence (descending k uses OLD row k-1)
__device__ __forceinline__ void step_sum(float x, const float (&wk)[KK],
                                         const float (&bk)[KK],
                                         float (&A)[KK][KK], float (&cv)[KK])
{
    float g[KK];
    #pragma unroll
    for (int k = 0; k < KK; ++k) g[k] = fmaf(x, wk[k], bk[k]);
    #pragma unroll
    for (int k = KK - 1; k >= 1; --k) {
        #pragma unroll
        for (int j = 0; j < k - 1; ++j)
            A[k][j] = fmaxf(A[k][j], g[k] + A[k - 1][j]);
        A[k][k - 1] = fmaxf(A[k][k - 1], g[k]);  // A[k-1][k-1] == 0 (diag)
        cv[k] = fmaxf(cv[k], g[k] + cv[k - 1]);
    }
    cv[0] = fmaxf(cv[0], g[0]);
}

// ---- pass 1: one block per (b, chunk); thread d = channel; 8-deep pipeline ----
constexpr int U1 = 8;
__global__ __launch_bounds__(256, 4) void pass1_summaries(
    const float* __restrict__ X, const float* __restrict__ W,
    const float* __restrict__ Bv, float* __restrict__ sum, int C, int L)
{
    const int b = blockIdx.x / C;
    const int c = blockIdx.x % C;
    const int d = threadIdx.x;

    float wk[KK], bk[KK];
    #pragma unroll
    for (int k = 0; k < KK; ++k) { wk[k] = W[k * DD + d]; bk[k] = Bv[k * DD + d]; }

    float cv[KK];
    float A[KK][KK];
    #pragma unroll
    for (int k = 0; k < KK; ++k) {
        cv[k] = -INFINITY;
        #pragma unroll
        for (int j = 0; j < KK; ++j) A[k][j] = -INFINITY;
    }

    const float* xp = X + ((long)b * TT + (long)c * L) * DD + d;
    const int nb = L / U1;                  // L in {32,64,128} -> nb even
    float x0[U1], x1[U1];
    #pragma unroll
    for (int u = 0; u < U1; ++u) x0[u] = xp[(long)u * DD];

    for (int ib = 0; ib < nb; ib += 2) {
        #pragma unroll
        for (int u = 0; u < U1; ++u) x1[u] = xp[(long)((ib + 1) * U1 + u) * DD];
        #pragma unroll
        for (int u = 0; u < U1; ++u) step_sum(x0[u], wk, bk, A, cv);
        if (ib + 2 < nb) {
            #pragma unroll
            for (int u = 0; u < U1; ++u) x0[u] = xp[(long)((ib + 2) * U1 + u) * DD];
        }
        #pragma unroll
        for (int u = 0; u < U1; ++u) step_sum(x1[u], wk, bk, A, cv);
    }

    float* sp = sum + (((long)b * C + c) * NSUM) * DD + d;
    #pragma unroll
    for (int k = 0; k < KK; ++k) sp[k * DD] = cv[k];
    #pragma unroll
    for (int k = 1; k < KK; ++k) {
        #pragma unroll
        for (int j = 0; j < k; ++j) sp[tri(k, j) * DD] = A[k][j];
    }
}

// ---- pass 2a: one block per (b, group); full map composition over G chunks ----
__global__ __launch_bounds__(256) void pass2a_groups(
    const float* __restrict__ sum, float* __restrict__ gsum, int C, int G)
{
    const int NG = C / G;
    const int b = blockIdx.x / NG;
    const int g = blockIdx.x % NG;
    const int d = threadIdx.x;

    float R[KK][KK], cv[KK];
    #pragma unroll
    for (int i = 0; i < KK; ++i) {
        cv[i] = -INFINITY;
        #pragma unroll
        for (int j = 0; j < KK; ++j) R[i][j] = -INFINITY;
    }

    for (int c = g * G; c < (g + 1) * G; ++c) {
        const float* sp = sum + (((long)b * C + c) * NSUM) * DD + d;
        float a2[KK][KK], c2[KK];
        #pragma unroll
        for (int i = 0; i < KK; ++i) c2[i] = sp[i * DD];
        #pragma unroll
        for (int i = 1; i < KK; ++i) {
            #pragma unroll
            for (int j = 0; j < i; ++j) a2[i][j] = sp[tri(i, j) * DD];
        }
        float nc[KK];
        #pragma unroll
        for (int i = 0; i < KK; ++i) {
            float v = fmaxf(c2[i], cv[i]);
            #pragma unroll
            for (int j = 0; j < i; ++j) v = fmaxf(v, a2[i][j] + cv[j]);
            nc[i] = v;
        }
        float nR[KK][KK];
        #pragma unroll
        for (int i = 1; i < KK; ++i) {
            #pragma unroll
            for (int j = 0; j < i; ++j) {
                float v = fmaxf(R[i][j], a2[i][j]);
                #pragma unroll
                for (int m = j + 1; m < i; ++m) v = fmaxf(v, a2[i][m] + R[m][j]);
                nR[i][j] = v;
            }
        }
        #pragma unroll
        for (int i = 0; i < KK; ++i) {
            cv[i] = nc[i];
            #pragma unroll
            for (int j = 0; j < i; ++j) R[i][j] = nR[i][j];
        }
    }

    float* gp = gsum + (((long)b * NG + g) * NSUM) * DD + d;
    #pragma unroll
    for (int i = 0; i < KK; ++i) gp[i * DD] = cv[i];
    #pragma unroll
    for (int i = 1; i < KK; ++i) {
        #pragma unroll
        for (int j = 0; j < i; ++j) gp[tri(i, j) * DD] = R[i][j];
    }
}

// apply a stored map (c + strict-lower A) to a concrete state s (in place)
__device__ __forceinline__ void apply_map(const float* __restrict__ sp,
                                          float (&s)[KK])
{
    float ns[KK];
    #pragma unroll
    for (int k = 0; k < KK; ++k) ns[k] = fmaxf(sp[k * DD], s[k]); // c[k], diag
    #pragma unroll
    for (int k = 1; k < KK; ++k) {
        #pragma unroll
        for (int j = 0; j < k; ++j)
            ns[k] = fmaxf(ns[k], sp[tri(k, j) * DD] + s[j]);
    }
    #pragma unroll
    for (int k = 0; k < KK; ++k) s[k] = ns[k];
}

// ---- pass 2b: one block per b; serial apply over NG group maps ----
__global__ __launch_bounds__(256) void pass2b_scan_groups(
    const float* __restrict__ gsum, float* __restrict__ ginfl, int NG)
{
    const int b = blockIdx.x;
    const int d = threadIdx.x;
    float s[KK];
    #pragma unroll
    for (int k = 0; k < KK; ++k) s[k] = -INFINITY;

    for (int g = 0; g < NG; ++g) {
        float* ip = ginfl + (((long)b * NG + g) * KK) * DD + d;
        #pragma unroll
        for (int k = 0; k < KK; ++k) ip[k * DD] = s[k];   // inflow BEFORE group g
        apply_map(gsum + (((long)b * NG + g) * NSUM) * DD + d, s);
    }
}

// ---- pass 2c: one block per (b, group); replay chunk maps -> chunk inflows ----
__global__ __launch_bounds__(256) void pass2c_chunk_inflows(
    const float* __restrict__ sum, const float* __restrict__ ginfl,
    float* __restrict__ infl, int C, int G)
{
    const int NG = C / G;
    const int b = blockIdx.x / NG;
    const int g = blockIdx.x % NG;
    const int d = threadIdx.x;

    float s[KK];
    const float* gp = ginfl + (((long)b * NG + g) * KK) * DD + d;
    #pragma unroll
    for (int k = 0; k < KK; ++k) s[k] = gp[k * DD];

    for (int c = g * G; c < (g + 1) * G; ++c) {
        float* ip = infl + (((long)b * C + c) * KK) * DD + d;
        #pragma unroll
        for (int k = 0; k < KK; ++k) ip[k * DD] = s[k];   // inflow BEFORE chunk c
        apply_map(sum + (((long)b * C + c) * NSUM) * DD + d, s);
    }
}

// ---- pass 3: one block (128 thr) per (b, chunk); float2/thread scan ----
__device__ __forceinline__ void step_scan2(float2 x, const float2 (&wk)[KK],
                                           const float2 (&bk)[KK], float2 (&s)[KK])
{
    float2 g[KK];
    #pragma unroll
    for (int k = 0; k < KK; ++k) {
        g[k].x = fmaf(x.x, wk[k].x, bk[k].x);
        g[k].y = fmaf(x.y, wk[k].y, bk[k].y);
    }
    #pragma unroll
    for (int k = KK - 1; k >= 1; --k) {
        s[k].x = fmaxf(s[k].x, s[k - 1].x + g[k].x);
        s[k].y = fmaxf(s[k].y, s[k - 1].y + g[k].y);
    }
    s[0].x = fmaxf(s[0].x, g[0].x);
    s[0].y = fmaxf(s[0].y, g[0].y);
}

constexpr int U3 = 8;
__global__ __launch_bounds__(128, 4) void pass3_scan(
    const float* __restrict__ X, const float* __restrict__ W,
    const float* __restrict__ Bv, const float* __restrict__ infl,
    float* __restrict__ out, int C, int L)
{
    const int b = blockIdx.x / C;
    const int c = blockIdx.x % C;
    const int d = threadIdx.x;              // channel pair: 2d, 2d+1

    const float2* W2 = (const float2*)W;
    const float2* B2 = (const float2*)Bv;
    float2 wk[KK], bk[KK];
    #pragma unroll
    for (int k = 0; k < KK; ++k) { wk[k] = W2[k * (DD/2) + d]; bk[k] = B2[k * (DD/2) + d]; }

    float2 s[KK];
    #pragma unroll
    for (int k = 0; k < KK; ++k) {
        const float2* ip = (const float2*)(infl + (((long)b * C + c) * KK + k) * DD);
        s[k] = ip[d];
    }

    const int t0 = c * L;
    const float2* xp = (const float2*)(X + ((long)b * TT + t0) * DD) + d;
    float* op = out + (long)b * TOUT * DD + 2 * d;

    const int nb = L / U3;                  // even
    float2 x0[U3], x1[U3];
    #pragma unroll
    for (int u = 0; u < U3; ++u) x0[u] = xp[(long)u * (DD/2)];

    int t = t0;
    for (int ib = 0; ib < nb; ib += 2) {
        #pragma unroll
        for (int u = 0; u < U3; ++u) x1[u] = xp[(long)((ib + 1) * U3 + u) * (DD/2)];
        #pragma unroll
        for (int u = 0; u < U3; ++u) {
            step_scan2(x0[u], wk, bk, s);
            if (t >= KK - 1) *(float2*)(op + (long)(t - (KK - 1)) * DD) = s[KK - 1];
            ++t;
        }
        if (ib + 2 < nb) {
            #pragma unroll
            for (int u = 0; u < U3; ++u) x0[u] = xp[(long)((ib + 2) * U3 + u) * (DD/2)];
        }
        #pragma unroll
        for (int u = 0; u < U3; ++u) {
            step_scan2(x1[u], wk, bk, s);
            if (t >= KK - 1) *(float2*)(op + (long)(t - (KK - 1)) * DD) = s[KK - 1];
            ++t;
        }
    }
}
} // namespace

extern "C" void kernel_launch(void* const* d_in, const int* in_sizes, int n_in,
                              void* d_out, int out_size, void* d_ws, size_t ws_size,
                              hipStream_t stream)
{
    const float* X  = (const float*)d_in[0];
    const float* W  = (const float*)d_in[1];
    const float* Bv = (const float*)d_in[2];
    float* out = (float*)d_out;

    // Largest chunk count (<=256) whose summaries+inflows+group arrays fit ws.
    int C = 256;
    int G, NG;
    for (;;) {
        NG = (C >= 16) ? 16 : C;
        G  = C / NG;
        size_t need = ((size_t)BB * C * (NSUM + KK) +
                       (size_t)BB * NG * (NSUM + KK)) * DD * sizeof(float);
        if (need <= ws_size || C <= 2) break;
        C >>= 1;
    }
    const int L = TT / C;

    float* sum   = (float*)d_ws;
    float* infl  = sum   + (size_t)BB * C  * NSUM * DD;
    float* gsum  = infl  + (size_t)BB * C  * KK   * DD;
    float* ginfl = gsum  + (size_t)BB * NG * NSUM * DD;

    pass1_summaries<<<BB * C, 256, 0, stream>>>(X, W, Bv, sum, C, L);
    pass2a_groups<<<BB * NG, 256, 0, stream>>>(sum, gsum, C, G);
    pass2b_scan_groups<<<BB, 256, 0, stream>>>(gsum, ginfl, NG);
    pass2c_chunk_inflows<<<BB * NG, 256, 0, stream>>>(sum, ginfl, infl, C, G);
    pass3_scan<<<BB * C, 128, 0, stream>>>(X, W, Bv, infl, out, C, L);
}